// Round 10
// baseline (1301.658 us; speedup 1.0000x reference)
//
#include <hip/hip_runtime.h>
#include <hip/hip_bf16.h>

typedef __attribute__((ext_vector_type(8))) short short8v;
typedef __attribute__((ext_vector_type(4))) float f32x4;
typedef __attribute__((ext_vector_type(8))) unsigned short us8;

#define LDA 264  // 256 + 8 bf16 pad; rows stay 16B-aligned (528 B)

__device__ __forceinline__ unsigned short f2bf(float f) {
  union { __hip_bfloat16 h; unsigned short u; } c;
  c.h = __float2bfloat16(f);
  return c.u;
}
__device__ __forceinline__ unsigned int f2bf2(float lo, float hi) {
  union { __hip_bfloat162 h; unsigned int u; } c;
  c.h = __float22bfloat162_rn(make_float2(lo, hi));
  return c.u;
}

// WA = (Wq@Wk^T)/16, WB = Wv@Wo, wb2 = (Wq@bk)/16, cq = (bq@Wk^T)/16,
// cv = bv@Wo, cb = (bk.bq)/16
__global__ __launch_bounds__(256) void make_w(
    const float* __restrict__ Wq, const float* __restrict__ Wk,
    const float* __restrict__ Wv, const float* __restrict__ Wo,
    const float* __restrict__ bq, const float* __restrict__ bk,
    const float* __restrict__ bv, float* __restrict__ WA,
    float* __restrict__ WB, float* __restrict__ wb2,
    float* __restrict__ cq, float* __restrict__ cv, float* __restrict__ cb) {
  __shared__ float wq[256], wv[256], bqs[256], bvs[256];
  const int i = blockIdx.x, t = threadIdx.x;
  wq[t] = Wq[i * 256 + t];
  wv[t] = Wv[i * 256 + t];
  bqs[t] = bq[t];
  bvs[t] = bv[t];
  __syncthreads();
  float sa = 0.f, sb = 0.f;
#pragma unroll 8
  for (int d = 0; d < 256; d++) {
    sa = fmaf(wq[d], Wk[t * 256 + d], sa);  // WA[i][t]
    sb = fmaf(wv[d], Wo[d * 256 + t], sb);  // WB[i][t]
  }
  WA[i * 256 + t] = sa * 0.0625f;
  WB[i * 256 + t] = sb;
  if (t == 0) {
    float s = 0.f;
#pragma unroll 8
    for (int d = 0; d < 256; d++) s = fmaf(wq[d], bk[d], s);
    wb2[i] = s * 0.0625f;
  }
  if (i == 0) {
    float s1 = 0.f, s2 = 0.f;
#pragma unroll 8
    for (int d = 0; d < 256; d++) {
      s1 = fmaf(bqs[d], Wk[t * 256 + d], s1);
      s2 = fmaf(bvs[d], Wo[d * 256 + t], s2);
    }
    cq[t] = s1 * 0.0625f;
    cv[t] = s2;
    if (t == 0) {
      float s = 0.f;
      for (int d = 0; d < 256; d++) s = fmaf(bk[d], bqs[d], s);
      cb[0] = s * 0.0625f;
    }
  }
}

// W2B[b][n][j] = (hs@WA)[n][j] + cq[j]   (bf16, B-operand for scores GEMM)
// V2B[b][c][n] = (hs@WB)^T[c][n] + cv[c] (bf16, B-operand for ctx GEMM)
// bn[b][n]     = hs[n]@wb2 + cb          (f32, softmax-axis bias)
__global__ __launch_bounds__(256) void prep2(
    const float* __restrict__ hs, const float* __restrict__ WA,
    const float* __restrict__ WB, const float* __restrict__ wb2,
    const float* __restrict__ cq, const float* __restrict__ cv,
    const float* __restrict__ cb, unsigned short* __restrict__ W2B,
    unsigned short* __restrict__ V2B, float* __restrict__ bn) {
  __shared__ float rows[8][256];
  __shared__ float w2s[256];
  const int tid = threadIdx.x;
  const int g0 = blockIdx.x * 8;
#pragma unroll
  for (int j = 0; j < 8; j++) rows[j][tid] = hs[(size_t)(g0 + j) * 256 + tid];
  w2s[tid] = wb2[tid];
  __syncthreads();
  const float cqv = cq[tid], cvv = cv[tid];
  float aq[8], av[8];
#pragma unroll
  for (int j = 0; j < 8; j++) { aq[j] = cqv; av[j] = cvv; }
#pragma unroll 8
  for (int i = 0; i < 256; i++) {
    const float wa = WA[i * 256 + tid];
    const float wb = WB[i * 256 + tid];
#pragma unroll
    for (int j = 0; j < 8; j++) {
      aq[j] = fmaf(rows[j][i], wa, aq[j]);
      av[j] = fmaf(rows[j][i], wb, av[j]);
    }
  }
  const int bb = g0 >> 8, n0 = g0 & 255;
#pragma unroll
  for (int j = 0; j < 8; j++)
    W2B[(size_t)(bb * 256 + n0 + j) * 256 + tid] = f2bf(aq[j]);
  us8 vp;
#pragma unroll
  for (int j = 0; j < 8; j++) vp[j] = f2bf(av[j]);
  *(us8*)(V2B + (size_t)(bb * 256 + tid) * 256 + n0) = vp;
  if (tid < 8) {
    float s = 0.f;
    for (int i = 0; i < 256; i++) s = fmaf(rows[tid][i], w2s[i], s);
    bn[bb * 256 + n0 + tid] = s + cb[0];
  }
}

// Barrier-free: each wave owns 16 rows x all 256 cols, self-contained
// pipeline: stage S -> GEMM-A -> in-reg softmax (P to own LDS region) ->
// GEMM-B -> in-reg LN -> store. NO __syncthreads anywhere.
__global__ __launch_bounds__(256, 4) void pair_attn8(
    const float* __restrict__ S, const float* __restrict__ bo,
    const float* __restrict__ gamma, const float* __restrict__ beta,
    const float* __restrict__ bn, const unsigned short* __restrict__ W2B,
    const unsigned short* __restrict__ V2B, float* __restrict__ out) {
  __shared__ unsigned short sP[4][16 * LDA];  // per-wave 16x256 tile (8.4KB)

  const int tid = threadIdx.x;
  const int wid = tid >> 6;
  const int lane = tid & 63;
  const int l16 = lane & 15;
  const int lhi = lane >> 4;

  // XCD-pinned batch via round-robin dispatch
  const int bid = blockIdx.x;
  const int bat = bid & 7;
  const int tile = bid >> 3;  // 0..1023: 64-row tile within batch

  const size_t base = ((size_t)(bat * 65536 + tile * 64)) * 256;
  const size_t wbase = base + (size_t)(wid * 16) * 256;  // wave's 16 rows
  const float* Sw = S + wbase;
  unsigned short* sp = sP[wid];

  // ---- stage wave's own 16 S rows (f32 -> bf16), coalesced 1KB/row
#pragma unroll
  for (int j = 0; j < 16; j++) {
    const float4 v = *(const float4*)(Sw + j * 256 + lane * 4);
    unsigned int* d = (unsigned int*)(sp + j * LDA + lane * 4);
    d[0] = f2bf2(v.x, v.y);
    d[1] = f2bf2(v.z, v.w);
  }

  const unsigned short* W2b = W2B + (size_t)bat * 65536;
  const unsigned short* V2b = V2B + (size_t)bat * 65536;
  const unsigned short* spA = sp + l16 * LDA + lhi * 8;  // A-frag base

  f32x4 acc[16];

  // ---- GEMM-A: scores[16 rows][256 n]; 1 ds_read + 16 B-loads + 16 MFMA /k
#pragma unroll
  for (int nt = 0; nt < 16; nt++) acc[nt] = (f32x4){0.f, 0.f, 0.f, 0.f};
#pragma unroll
  for (int kt = 0; kt < 8; kt++) {
    const short8v a = *(const short8v*)(spA + kt * 32);
    const unsigned short* Bk = W2b + l16 * 256 + lhi * 8 + kt * 32;
#pragma unroll
    for (int nt = 0; nt < 16; nt++) {
      const short8v b = *(const short8v*)(Bk + nt * 4096);
      acc[nt] =
          __builtin_amdgcn_mfma_f32_16x16x32_bf16(a, b, acc[nt], 0, 0, 0);
    }
  }

  // ---- softmax: p = exp(s + bn); row-sums complete via 4 shfl (l16 group);
  //      unnormalized P overwrites the wave's own LDS tile (intra-wave dep,
  //      lgkmcnt-ordered, no barrier).
  float bnl[16];
#pragma unroll
  for (int nt = 0; nt < 16; nt++) bnl[nt] = bn[bat * 256 + nt * 16 + l16];
  float psum[4] = {0.f, 0.f, 0.f, 0.f};
#pragma unroll
  for (int nt = 0; nt < 16; nt++)
#pragma unroll
    for (int rg = 0; rg < 4; rg++) {
      const float p = __expf(acc[nt][rg] + bnl[nt]);
      psum[rg] += p;
      sp[(lhi * 4 + rg) * LDA + nt * 16 + l16] = f2bf(p);
    }
#pragma unroll
  for (int rg = 0; rg < 4; rg++) {
    psum[rg] += __shfl_xor(psum[rg], 1);
    psum[rg] += __shfl_xor(psum[rg], 2);
    psum[rg] += __shfl_xor(psum[rg], 4);
    psum[rg] += __shfl_xor(psum[rg], 8);
  }

  // ---- GEMM-B: o[16 rows][256 d] = P_un @ V2
#pragma unroll
  for (int ct = 0; ct < 16; ct++) acc[ct] = (f32x4){0.f, 0.f, 0.f, 0.f};
#pragma unroll
  for (int kt = 0; kt < 8; kt++) {
    const short8v a = *(const short8v*)(spA + kt * 32);
    const unsigned short* Bk = V2b + l16 * 256 + lhi * 8 + kt * 32;
#pragma unroll
    for (int ct = 0; ct < 16; ct++) {
      const short8v b = *(const short8v*)(Bk + ct * 4096);
      acc[ct] =
          __builtin_amdgcn_mfma_f32_16x16x32_bf16(a, b, acc[ct], 0, 0, 0);
    }
  }

  // ---- epilogue: o/rowsum + bo + S residual (f32, L2-hot), LN in-register
  float invr[4];
#pragma unroll
  for (int rg = 0; rg < 4; rg++) invr[rg] = 1.f / psum[rg];

  float s1[4] = {0.f, 0.f, 0.f, 0.f}, s2[4] = {0.f, 0.f, 0.f, 0.f};
#pragma unroll
  for (int nt = 0; nt < 16; nt++) {
    const int col = nt * 16 + l16;
    const float bov = bo[col];
#pragma unroll
    for (int rg = 0; rg < 4; rg++) {
      const float val =
          acc[nt][rg] * invr[rg] + bov + Sw[(lhi * 4 + rg) * 256 + col];
      acc[nt][rg] = val;
      s1[rg] += val;
      s2[rg] = fmaf(val, val, s2[rg]);
    }
  }
#pragma unroll
  for (int rg = 0; rg < 4; rg++) {
    s1[rg] += __shfl_xor(s1[rg], 1); s2[rg] += __shfl_xor(s2[rg], 1);
    s1[rg] += __shfl_xor(s1[rg], 2); s2[rg] += __shfl_xor(s2[rg], 2);
    s1[rg] += __shfl_xor(s1[rg], 4); s2[rg] += __shfl_xor(s2[rg], 4);
    s1[rg] += __shfl_xor(s1[rg], 8); s2[rg] += __shfl_xor(s2[rg], 8);
  }
  float mean[4], rstd[4];
#pragma unroll
  for (int rg = 0; rg < 4; rg++) {
    mean[rg] = s1[rg] * (1.f / 256.f);
    const float ex2 = s2[rg] * (1.f / 256.f);
    rstd[rg] = rsqrtf(ex2 - mean[rg] * mean[rg] + 1e-5f);
  }
  float* Ow = out + wbase;
#pragma unroll
  for (int nt = 0; nt < 16; nt++) {
    const int col = nt * 16 + l16;
    const float gvv = gamma[col], bev = beta[col];
#pragma unroll
    for (int rg = 0; rg < 4; rg++)
      Ow[(lhi * 4 + rg) * 256 + col] =
          (acc[nt][rg] - mean[rg]) * rstd[rg] * gvv + bev;
  }
}

extern "C" void kernel_launch(void* const* d_in, const int* in_sizes, int n_in,
                              void* d_out, int out_size, void* d_ws, size_t ws_size,
                              hipStream_t stream) {
  const float* hs    = (const float*)d_in[0];
  const float* S     = (const float*)d_in[1];
  const float* Wq    = (const float*)d_in[2];
  const float* bq    = (const float*)d_in[3];
  const float* Wk    = (const float*)d_in[4];
  const float* bk    = (const float*)d_in[5];
  const float* Wv    = (const float*)d_in[6];
  const float* bv    = (const float*)d_in[7];
  const float* Wo    = (const float*)d_in[8];
  const float* bo    = (const float*)d_in[9];
  const float* gamma = (const float*)d_in[10];
  const float* beta  = (const float*)d_in[11];

  unsigned short* W2B = (unsigned short*)d_ws;          // 8*256*256 bf16 = 1MB
  unsigned short* V2B = W2B + 8 * 256 * 256;            // 1MB
  float* WA  = (float*)(V2B + 8 * 256 * 256);           // 256KB
  float* WB  = WA + 256 * 256;                          // 256KB
  float* wb2 = WB + 256 * 256;                          // 1KB
  float* cq  = wb2 + 256;
  float* cv  = cq + 256;
  float* cb  = cv + 256;
  float* bnp = cb + 256;                                // 8*256 f32

  make_w<<<256, 256, 0, stream>>>(Wq, Wk, Wv, Wo, bq, bk, bv, WA, WB, wb2, cq,
                                  cv, cb);
  prep2<<<256, 256, 0, stream>>>(hs, WA, WB, wb2, cq, cv, cb, W2B, V2B, bnp);
  pair_attn8<<<8192, 256, 0, stream>>>(S, bo, gamma, beta, bnp, W2B, V2B,
                                       (float*)d_out);
}

// Round 11
// 524.488 us; speedup vs baseline: 2.4818x; 2.4818x over previous
//
#include <hip/hip_runtime.h>
#include <hip/hip_bf16.h>

typedef __attribute__((ext_vector_type(8))) short short8v;
typedef __attribute__((ext_vector_type(4))) float f32x4;
typedef __attribute__((ext_vector_type(8))) unsigned short us8;
typedef const __attribute__((address_space(1))) void* gas_t;
typedef __attribute__((address_space(3))) void* las_t;

#define LDA 264  // 256 + 8 bf16 pad for the S/P tile

__device__ __forceinline__ unsigned short f2bf(float f) {
  union { __hip_bfloat16 h; unsigned short u; } c;
  c.h = __float2bfloat16(f);
  return c.u;
}
__device__ __forceinline__ unsigned int f2bf2(float lo, float hi) {
  union { __hip_bfloat162 h; unsigned int u; } c;
  c.h = __float22bfloat162_rn(make_float2(lo, hi));
  return c.u;
}

// WA = (Wq@Wk^T)/16, WB = Wv@Wo, wb2 = (Wq@bk)/16, cq = (bq@Wk^T)/16,
// cv = bv@Wo, cb = (bk.bq)/16
__global__ __launch_bounds__(256) void make_w(
    const float* __restrict__ Wq, const float* __restrict__ Wk,
    const float* __restrict__ Wv, const float* __restrict__ Wo,
    const float* __restrict__ bq, const float* __restrict__ bk,
    const float* __restrict__ bv, float* __restrict__ WA,
    float* __restrict__ WB, float* __restrict__ wb2,
    float* __restrict__ cq, float* __restrict__ cv, float* __restrict__ cb) {
  __shared__ float wq[256], wv[256], bqs[256], bvs[256];
  const int i = blockIdx.x, t = threadIdx.x;
  wq[t] = Wq[i * 256 + t];
  wv[t] = Wv[i * 256 + t];
  bqs[t] = bq[t];
  bvs[t] = bv[t];
  __syncthreads();
  float sa = 0.f, sb = 0.f;
#pragma unroll 8
  for (int d = 0; d < 256; d++) {
    sa = fmaf(wq[d], Wk[t * 256 + d], sa);  // WA[i][t]
    sb = fmaf(wv[d], Wo[d * 256 + t], sb);  // WB[i][t]
  }
  WA[i * 256 + t] = sa * 0.0625f;
  WB[i * 256 + t] = sb;
  if (t == 0) {
    float s = 0.f;
#pragma unroll 8
    for (int d = 0; d < 256; d++) s = fmaf(wq[d], bk[d], s);
    wb2[i] = s * 0.0625f;
  }
  if (i == 0) {
    float s1 = 0.f, s2 = 0.f;
#pragma unroll 8
    for (int d = 0; d < 256; d++) {
      s1 = fmaf(bqs[d], Wk[t * 256 + d], s1);
      s2 = fmaf(bvs[d], Wo[d * 256 + t], s2);
    }
    cq[t] = s1 * 0.0625f;
    cv[t] = s2;
    if (t == 0) {
      float s = 0.f;
      for (int d = 0; d < 256; d++) s = fmaf(bk[d], bqs[d], s);
      cb[0] = s * 0.0625f;
    }
  }
}

// k-chunk-major B layouts for async LDS staging:
// W2c[b][kc=k>>5][n][k&31]  (scores B: col=n token, k=dim)
// V2c[b][kc=n>>5][c][n&31]  (ctx    B: col=c dim,   k=n token)
// bn[b][n] = hs[n]@wb2 + cb
__global__ __launch_bounds__(256) void prep2(
    const float* __restrict__ hs, const float* __restrict__ WA,
    const float* __restrict__ WB, const float* __restrict__ wb2,
    const float* __restrict__ cq, const float* __restrict__ cv,
    const float* __restrict__ cb, unsigned short* __restrict__ W2c,
    unsigned short* __restrict__ V2c, float* __restrict__ bn) {
  __shared__ float rows[8][256];
  __shared__ float w2s[256];
  const int tid = threadIdx.x;
  const int g0 = blockIdx.x * 8;
#pragma unroll
  for (int j = 0; j < 8; j++) rows[j][tid] = hs[(size_t)(g0 + j) * 256 + tid];
  w2s[tid] = wb2[tid];
  __syncthreads();
  const float cqv = cq[tid], cvv = cv[tid];
  float aq[8], av[8];
#pragma unroll
  for (int j = 0; j < 8; j++) { aq[j] = cqv; av[j] = cvv; }
#pragma unroll 8
  for (int i = 0; i < 256; i++) {
    const float wa = WA[i * 256 + tid];
    const float wb = WB[i * 256 + tid];
#pragma unroll
    for (int j = 0; j < 8; j++) {
      aq[j] = fmaf(rows[j][i], wa, aq[j]);
      av[j] = fmaf(rows[j][i], wb, av[j]);
    }
  }
  const int bb = g0 >> 8, n0 = g0 & 255;
  // W2c: element (n=n0+j, k=tid)
#pragma unroll
  for (int j = 0; j < 8; j++)
    W2c[bb * 65536 + (tid >> 5) * 8192 + (n0 + j) * 32 + (tid & 31)] =
        f2bf(aq[j]);
  // V2c: element (c=tid, n=n0+j); n0 multiple of 8 -> same 32-chunk
  us8 vp;
#pragma unroll
  for (int j = 0; j < 8; j++) vp[j] = f2bf(av[j]);
  *(us8*)(V2c + bb * 65536 + (n0 >> 5) * 8192 + tid * 32 + (n0 & 31)) = vp;
  if (tid < 8) {
    float s = 0.f;
    for (int i = 0; i < 256; i++) s = fmaf(rows[tid][i], w2s[i], s);
    bn[bb * 256 + n0 + tid] = s + cb[0];
  }
}

// Stage one wave-private 4KB B-chunk (64 cols x 32 k, bf16) into LDS via
// async global_load_lds. LDS dest is wave-uniform base; HW adds lane*16.
__device__ __forceinline__ void stage_b(const unsigned short* src_wave,
                                        unsigned short* lds_wave, int lane) {
#pragma unroll
  for (int i = 0; i < 4; i++) {
    const unsigned short* g = src_wave + i * 512 + lane * 8;
    unsigned short* l = lds_wave + i * 512;
    __builtin_amdgcn_global_load_lds((gas_t)g, (las_t)l, 16, 0, 0);
  }
}

// One block: 64 r-rows of one (b,l) pair. B-operand double-buffered in LDS
// via global_load_lds + counted vmcnt (wave-private chunks -> no barriers in
// the GEMM loops). Raw s_barrier around the exp phase keeps V-loads in flight.
__global__ __launch_bounds__(256, 2) void pair_attn9(
    const float* __restrict__ S, const float* __restrict__ bo,
    const float* __restrict__ gamma, const float* __restrict__ beta,
    const float* __restrict__ bn, const unsigned short* __restrict__ W2c,
    const unsigned short* __restrict__ V2c, float* __restrict__ out) {
  __shared__ unsigned short sA[64 * LDA];  // S (bf16), then P (bf16)
  __shared__ unsigned short sB[2][8192];   // 2 x 16KB B-chunk double buffer
  __shared__ float sRed[64 * 8];           // LN partial sums

  const int tid = threadIdx.x;
  const int w = tid >> 6;
  const int lane = tid & 63;
  const int l16 = lane & 15;
  const int lhi = lane >> 4;
  // bijective XCD swizzle: 8192 wgs, 8 XCDs -> each XCD owns one batch
  const int bid = blockIdx.x;
  const int idx = (bid & 7) * 1024 + (bid >> 3);
  const int rblk = idx & 3;
  const int lrow = (idx >> 2) & 255;
  const int bat = idx >> 10;

  const size_t base = ((size_t)((bat * 256 + lrow) * 256 + rblk * 64)) * 256;
  const float* Sblk = S + base;

  // ---- stage S rows -> sA (bf16), 16B LDS writes
#pragma unroll
  for (int it = 0; it < 8; it++) {
    const int c = tid + it * 256;
    const int row = c >> 5, col = (c & 31) << 3;
    const float4 u = *(const float4*)(Sblk + row * 256 + col);
    const float4 v = *(const float4*)(Sblk + row * 256 + col + 4);
    us8 p;
    unsigned int* pu = (unsigned int*)&p;
    pu[0] = f2bf2(u.x, u.y);
    pu[1] = f2bf2(u.z, u.w);
    pu[2] = f2bf2(v.x, v.y);
    pu[3] = f2bf2(v.z, v.w);
    *(us8*)(sA + row * LDA + col) = p;
  }
  // softmax bias (the ONLY global load allowed before the fenced region)
  float bnv[4];
#pragma unroll
  for (int nt = 0; nt < 4; nt++)
    bnv[nt] = bn[bat * 256 + w * 64 + nt * 16 + l16];
  __syncthreads();  // B1 (drains all vmem)

  const unsigned short* W2b = W2c + (size_t)bat * 65536;
  const unsigned short* V2b = V2c + (size_t)bat * 65536;

  // ===== fenced VMEM region: only our global_load_lds in flight =====
  asm volatile("s_waitcnt vmcnt(0)" ::: "memory");
  __builtin_amdgcn_sched_barrier(0);

  // prologue: chunks 0,1 of W
  stage_b(W2b + 0 * 8192 + w * 2048, &sB[0][w * 2048], lane);
  stage_b(W2b + 1 * 8192 + w * 2048, &sB[1][w * 2048], lane);

  f32x4 acc[4][4];
#pragma unroll
  for (int rt = 0; rt < 4; rt++)
#pragma unroll
    for (int nt = 0; nt < 4; nt++) acc[rt][nt] = (f32x4){0.f, 0.f, 0.f, 0.f};

  // ---- GEMM-A: scores = S @ W2 (8 chunks, dbuf, per-wave pipeline)
#pragma unroll
  for (int q = 0; q < 8; q++) {
    asm volatile("s_waitcnt vmcnt(4)" ::: "memory");  // chunk q arrived
    __builtin_amdgcn_sched_barrier(0);
    const unsigned short* bb = &sB[q & 1][w * 2048];
    short8v a[4], bf[4];
#pragma unroll
    for (int rt = 0; rt < 4; rt++)
      a[rt] = *(const short8v*)(sA + (rt * 16 + l16) * LDA + q * 32 + lhi * 8);
#pragma unroll
    for (int nt = 0; nt < 4; nt++)
      bf[nt] = *(const short8v*)(bb + (nt * 16 + l16) * 32 + lhi * 8);
#pragma unroll
    for (int rt = 0; rt < 4; rt++)
#pragma unroll
      for (int nt = 0; nt < 4; nt++)
        acc[rt][nt] = __builtin_amdgcn_mfma_f32_16x16x32_bf16(
            a[rt], bf[nt], acc[rt][nt], 0, 0, 0);
    asm volatile("s_waitcnt lgkmcnt(0)" ::: "memory");  // reads serviced
    __builtin_amdgcn_sched_barrier(0);
    if (q < 6)
      stage_b(W2b + (q + 2) * 8192 + w * 2048, &sB[q & 1][w * 2048], lane);
    else  // V chunks 0,1 issued under the exp phase
      stage_b(V2b + (q - 6) * 8192 + w * 2048, &sB[q & 1][w * 2048], lane);
  }

  // ---- exp phase between raw barriers (NO vmcnt drain: V0/V1 in flight)
  asm volatile("s_waitcnt lgkmcnt(0)" ::: "memory");
  __builtin_amdgcn_s_barrier();  // all waves done reading sA (S)
#pragma unroll
  for (int rt = 0; rt < 4; rt++)
#pragma unroll
    for (int nt = 0; nt < 4; nt++)
#pragma unroll
      for (int rg = 0; rg < 4; rg++)
        sA[(rt * 16 + lhi * 4 + rg) * LDA + (w * 64 + nt * 16 + l16)] =
            f2bf(__expf(acc[rt][nt][rg] + bnv[nt]));
  asm volatile("s_waitcnt lgkmcnt(0)" ::: "memory");
  __builtin_amdgcn_s_barrier();  // P visible to all waves

  // ---- GEMM-B: o = P_un @ V2, plus P row-sums via ones-MFMA
  short8v onesv;
#pragma unroll
  for (int j = 0; j < 8; j++) onesv[j] = (short)0x3F80;  // bf16 1.0
  f32x4 ps[4];
#pragma unroll
  for (int rt = 0; rt < 4; rt++) {
    ps[rt] = (f32x4){0.f, 0.f, 0.f, 0.f};
#pragma unroll
    for (int nt = 0; nt < 4; nt++) acc[rt][nt] = (f32x4){0.f, 0.f, 0.f, 0.f};
  }
#pragma unroll
  for (int q = 0; q < 8; q++) {
    if (q < 7) {
      asm volatile("s_waitcnt vmcnt(4)" ::: "memory");
    } else {
      asm volatile("s_waitcnt vmcnt(0)" ::: "memory");
    }
    __builtin_amdgcn_sched_barrier(0);
    const unsigned short* bb = &sB[q & 1][w * 2048];
    short8v a[4], bf[4];
#pragma unroll
    for (int rt = 0; rt < 4; rt++)
      a[rt] = *(const short8v*)(sA + (rt * 16 + l16) * LDA + q * 32 + lhi * 8);
#pragma unroll
    for (int nt = 0; nt < 4; nt++)
      bf[nt] = *(const short8v*)(bb + (nt * 16 + l16) * 32 + lhi * 8);
#pragma unroll
    for (int rt = 0; rt < 4; rt++) {
#pragma unroll
      for (int nt = 0; nt < 4; nt++)
        acc[rt][nt] = __builtin_amdgcn_mfma_f32_16x16x32_bf16(
            a[rt], bf[nt], acc[rt][nt], 0, 0, 0);
      ps[rt] = __builtin_amdgcn_mfma_f32_16x16x32_bf16(a[rt], onesv, ps[rt],
                                                       0, 0, 0);
    }
    asm volatile("s_waitcnt lgkmcnt(0)" ::: "memory");
    __builtin_amdgcn_sched_barrier(0);
    if (q < 6)
      stage_b(V2b + (q + 2) * 8192 + w * 2048, &sB[q & 1][w * 2048], lane);
  }
  __builtin_amdgcn_sched_barrier(0);
  // ===== end fenced region =====

  // ---- epilogue: o/rowsum + bo + S residual (f32), LN partial sums
  float bov[4], gv[4], bev[4];
#pragma unroll
  for (int nt = 0; nt < 4; nt++) {
    const int col = w * 64 + nt * 16 + l16;
    bov[nt] = bo[col];
    gv[nt] = gamma[col];
    bev[nt] = beta[col];
  }
#pragma unroll
  for (int rt = 0; rt < 4; rt++)
#pragma unroll
    for (int rg = 0; rg < 4; rg++) {
      const int row = rt * 16 + lhi * 4 + rg;
      const float invr = 1.f / ps[rt][rg];
      const float* Srow = Sblk + row * 256;
      float s1 = 0.f, s2 = 0.f;
#pragma unroll
      for (int nt = 0; nt < 4; nt++) {
        const int col = w * 64 + nt * 16 + l16;
        const float val = acc[rt][nt][rg] * invr + bov[nt] + Srow[col];
        acc[rt][nt][rg] = val;
        s1 += val;
        s2 = fmaf(val, val, s2);
      }
      s1 += __shfl_xor(s1, 1); s2 += __shfl_xor(s2, 1);
      s1 += __shfl_xor(s1, 2); s2 += __shfl_xor(s2, 2);
      s1 += __shfl_xor(s1, 4); s2 += __shfl_xor(s2, 4);
      s1 += __shfl_xor(s1, 8); s2 += __shfl_xor(s2, 8);
      if (l16 == 0) { sRed[row * 8 + w] = s1; sRed[row * 8 + 4 + w] = s2; }
    }
  __syncthreads();  // B4

  float* O = out + base;
#pragma unroll
  for (int rt = 0; rt < 4; rt++)
#pragma unroll
    for (int rg = 0; rg < 4; rg++) {
      const int row = rt * 16 + lhi * 4 + rg;
      f32x4 sa = *(f32x4*)(sRed + row * 8);
      f32x4 sq = *(f32x4*)(sRed + row * 8 + 4);
      const float mean = (sa[0] + sa[1] + sa[2] + sa[3]) * (1.f / 256.f);
      const float ex2 = (sq[0] + sq[1] + sq[2] + sq[3]) * (1.f / 256.f);
      const float rstd = rsqrtf(ex2 - mean * mean + 1e-5f);
      float* Orow = O + row * 256;
#pragma unroll
      for (int nt = 0; nt < 4; nt++) {
        const int col = w * 64 + nt * 16 + l16;
        Orow[col] = (acc[rt][nt][rg] - mean) * rstd * gv[nt] + bev[nt];
      }
    }
}

extern "C" void kernel_launch(void* const* d_in, const int* in_sizes, int n_in,
                              void* d_out, int out_size, void* d_ws, size_t ws_size,
                              hipStream_t stream) {
  const float* hs    = (const float*)d_in[0];
  const float* S     = (const float*)d_in[1];
  const float* Wq    = (const float*)d_in[2];
  const float* bq    = (const float*)d_in[3];
  const float* Wk    = (const float*)d_in[4];
  const float* bk    = (const float*)d_in[5];
  const float* Wv    = (const float*)d_in[6];
  const float* bv    = (const float*)d_in[7];
  const float* Wo    = (const float*)d_in[8];
  const float* bo    = (const float*)d_in[9];
  const float* gamma = (const float*)d_in[10];
  const float* beta  = (const float*)d_in[11];

  unsigned short* W2c = (unsigned short*)d_ws;          // 8*256*256 bf16 = 1MB
  unsigned short* V2c = W2c + 8 * 256 * 256;            // 1MB
  float* WA  = (float*)(V2c + 8 * 256 * 256);           // 256KB
  float* WB  = WA + 256 * 256;                          // 256KB
  float* wb2 = WB + 256 * 256;                          // 1KB
  float* cq  = wb2 + 256;
  float* cv  = cq + 256;
  float* cb  = cv + 256;
  float* bnp = cb + 256;                                // 8*256 f32

  make_w<<<256, 256, 0, stream>>>(Wq, Wk, Wv, Wo, bq, bk, bv, WA, WB, wb2, cq,
                                  cv, cb);
  prep2<<<256, 256, 0, stream>>>(hs, WA, WB, wb2, cq, cv, cb, W2c, V2c, bnp);
  pair_attn9<<<8192, 256, 0, stream>>>(S, bo, gamma, beta, bnp, W2c, V2c,
                                       (float*)d_out);
}

// Round 12
// 509.751 us; speedup vs baseline: 2.5535x; 1.0289x over previous
//
#include <hip/hip_runtime.h>
#include <hip/hip_bf16.h>

typedef __attribute__((ext_vector_type(8))) short short8v;
typedef __attribute__((ext_vector_type(4))) float f32x4;
typedef __attribute__((ext_vector_type(8))) unsigned short us8;
typedef const __attribute__((address_space(1))) void* gas_t;
typedef __attribute__((address_space(3))) void* las_t;

#define LDA 264  // 256 + 8 bf16 pad for the S/P tile

__device__ __forceinline__ unsigned short f2bf(float f) {
  union { __hip_bfloat16 h; unsigned short u; } c;
  c.h = __float2bfloat16(f);
  return c.u;
}
__device__ __forceinline__ unsigned int f2bf2(float lo, float hi) {
  union { __hip_bfloat162 h; unsigned int u; } c;
  c.h = __float22bfloat162_rn(make_float2(lo, hi));
  return c.u;
}

// WA = (Wq@Wk^T)/16, WB = Wv@Wo, wb2 = (Wq@bk)/16, cq = (bq@Wk^T)/16,
// cv = bv@Wo, cb = (bk.bq)/16
__global__ __launch_bounds__(256) void make_w(
    const float* __restrict__ Wq, const float* __restrict__ Wk,
    const float* __restrict__ Wv, const float* __restrict__ Wo,
    const float* __restrict__ bq, const float* __restrict__ bk,
    const float* __restrict__ bv, float* __restrict__ WA,
    float* __restrict__ WB, float* __restrict__ wb2,
    float* __restrict__ cq, float* __restrict__ cv, float* __restrict__ cb) {
  __shared__ float wq[256], wv[256], bqs[256], bvs[256];
  const int i = blockIdx.x, t = threadIdx.x;
  wq[t] = Wq[i * 256 + t];
  wv[t] = Wv[i * 256 + t];
  bqs[t] = bq[t];
  bvs[t] = bv[t];
  __syncthreads();
  float sa = 0.f, sb = 0.f;
#pragma unroll 8
  for (int d = 0; d < 256; d++) {
    sa = fmaf(wq[d], Wk[t * 256 + d], sa);  // WA[i][t]
    sb = fmaf(wv[d], Wo[d * 256 + t], sb);  // WB[i][t]
  }
  WA[i * 256 + t] = sa * 0.0625f;
  WB[i * 256 + t] = sb;
  if (t == 0) {
    float s = 0.f;
#pragma unroll 8
    for (int d = 0; d < 256; d++) s = fmaf(wq[d], bk[d], s);
    wb2[i] = s * 0.0625f;
  }
  if (i == 0) {
    float s1 = 0.f, s2 = 0.f;
#pragma unroll 8
    for (int d = 0; d < 256; d++) {
      s1 = fmaf(bqs[d], Wk[t * 256 + d], s1);
      s2 = fmaf(bvs[d], Wo[d * 256 + t], s2);
    }
    cq[t] = s1 * 0.0625f;
    cv[t] = s2;
    if (t == 0) {
      float s = 0.f;
      for (int d = 0; d < 256; d++) s = fmaf(bk[d], bqs[d], s);
      cb[0] = s * 0.0625f;
    }
  }
}

// Chunk-major, MFMA-fragment-contiguous B layouts. Wave chunk (4KB) layout:
//   [nt:4][lhi:4][l16:16][j:8]  ->  lane (lhi*16+l16) reads frag nt at
//   byte  nt*1024 + lane*16  (perfectly coalesced, conflict-free ds_read).
// W2c: element (n, k):  idx = b*65536 + (k>>5)*8192 + (n>>6)*2048
//                           + ((n>>4)&3)*512 + ((k>>3)&3)*128 + (n&15)*8 + (k&7)
// V2c: element (c, n):  idx = b*65536 + (n>>5)*8192 + (c>>6)*2048
//                           + ((c>>4)&3)*512 + ((n>>3)&3)*128 + (c&15)*8 + (n&7)
// bn[b][n] = hs[n]@wb2 + cb
__global__ __launch_bounds__(256) void prep2(
    const float* __restrict__ hs, const float* __restrict__ WA,
    const float* __restrict__ WB, const float* __restrict__ wb2,
    const float* __restrict__ cq, const float* __restrict__ cv,
    const float* __restrict__ cb, unsigned short* __restrict__ W2c,
    unsigned short* __restrict__ V2c, float* __restrict__ bn) {
  __shared__ float rows[8][256];
  __shared__ float w2s[256];
  const int tid = threadIdx.x;
  const int g0 = blockIdx.x * 8;
#pragma unroll
  for (int j = 0; j < 8; j++) rows[j][tid] = hs[(size_t)(g0 + j) * 256 + tid];
  w2s[tid] = wb2[tid];
  __syncthreads();
  const float cqv = cq[tid], cvv = cv[tid];
  float aq[8], av[8];
#pragma unroll
  for (int j = 0; j < 8; j++) { aq[j] = cqv; av[j] = cvv; }
#pragma unroll 8
  for (int i = 0; i < 256; i++) {
    const float wa = WA[i * 256 + tid];
    const float wb = WB[i * 256 + tid];
#pragma unroll
    for (int j = 0; j < 8; j++) {
      aq[j] = fmaf(rows[j][i], wa, aq[j]);
      av[j] = fmaf(rows[j][i], wb, av[j]);
    }
  }
  const int bb = g0 >> 8, n0 = g0 & 255;
  // W2c: thread holds k=tid for n=n0..n0+7
  {
    const int kc = tid >> 5, lhi = (tid >> 3) & 3, j = tid & 7;
    const int w = n0 >> 6, nt = (n0 >> 4) & 3, l0 = n0 & 15;
    unsigned short* dst = W2c + bb * 65536 + kc * 8192 + w * 2048 + nt * 512 +
                          lhi * 128 + l0 * 8 + j;
#pragma unroll
    for (int jj = 0; jj < 8; jj++) dst[jj * 8] = f2bf(aq[jj]);
  }
  // V2c: thread holds c=tid for n=n0..n0+7 (contiguous j -> us8)
  {
    const int kc = n0 >> 5, lhi = (n0 >> 3) & 3;
    const int w = tid >> 6, nt = (tid >> 4) & 3, l16 = tid & 15;
    us8 vp;
#pragma unroll
    for (int j = 0; j < 8; j++) vp[j] = f2bf(av[j]);
    *(us8*)(V2c + bb * 65536 + kc * 8192 + w * 2048 + nt * 512 + lhi * 128 +
            l16 * 8) = vp;
  }
  if (tid < 8) {
    float s = 0.f;
    for (int i = 0; i < 256; i++) s = fmaf(rows[tid][i], w2s[i], s);
    bn[bb * 256 + n0 + tid] = s + cb[0];
  }
}

// Stage one wave-private 4KB B-chunk into LDS (identity copy; layout already
// fragment-contiguous). LDS dest wave-uniform base; HW adds lane*16.
__device__ __forceinline__ void stage_b(const unsigned short* src_wave,
                                        unsigned short* lds_wave, int lane) {
#pragma unroll
  for (int i = 0; i < 4; i++) {
    const unsigned short* g = src_wave + i * 512 + lane * 8;
    unsigned short* l = lds_wave + i * 512;
    __builtin_amdgcn_global_load_lds((gas_t)g, (las_t)l, 16, 0, 0);
  }
}

// One block: 64 r-rows of one (b,l) pair. B double-buffered in LDS via
// global_load_lds + counted vmcnt; stage issued BEFORE the MFMAs (2-chunk
// in-flight window). Raw s_barrier around exp keeps V-loads in flight.
__global__ __launch_bounds__(256, 2) void pair_attn10(
    const float* __restrict__ S, const float* __restrict__ bo,
    const float* __restrict__ gamma, const float* __restrict__ beta,
    const float* __restrict__ bn, const unsigned short* __restrict__ W2c,
    const unsigned short* __restrict__ V2c, float* __restrict__ out) {
  __shared__ unsigned short sA[64 * LDA];  // S (bf16), then P (bf16)
  __shared__ unsigned short sB[2][8192];   // 2 x 16KB B-chunk double buffer
  __shared__ float sRed[64 * 8];           // LN partial sums

  const int tid = threadIdx.x;
  const int w = tid >> 6;
  const int lane = tid & 63;
  const int l16 = lane & 15;
  const int lhi = lane >> 4;
  // bijective XCD swizzle: 8192 wgs, 8 XCDs -> each XCD owns one batch
  const int bid = blockIdx.x;
  const int idx = (bid & 7) * 1024 + (bid >> 3);
  const int rblk = idx & 3;
  const int lrow = (idx >> 2) & 255;
  const int bat = idx >> 10;

  const size_t base = ((size_t)((bat * 256 + lrow) * 256 + rblk * 64)) * 256;
  const float* Sblk = S + base;

  // ---- stage S rows -> sA (bf16), 16B LDS writes
#pragma unroll
  for (int it = 0; it < 8; it++) {
    const int c = tid + it * 256;
    const int row = c >> 5, col = (c & 31) << 3;
    const float4 u = *(const float4*)(Sblk + row * 256 + col);
    const float4 v = *(const float4*)(Sblk + row * 256 + col + 4);
    us8 p;
    unsigned int* pu = (unsigned int*)&p;
    pu[0] = f2bf2(u.x, u.y);
    pu[1] = f2bf2(u.z, u.w);
    pu[2] = f2bf2(v.x, v.y);
    pu[3] = f2bf2(v.z, v.w);
    *(us8*)(sA + row * LDA + col) = p;
  }
  // softmax bias (the ONLY global load before the fenced region)
  float bnv[4];
#pragma unroll
  for (int nt = 0; nt < 4; nt++)
    bnv[nt] = bn[bat * 256 + w * 64 + nt * 16 + l16];
  __syncthreads();  // B1 (drains all vmem)

  const unsigned short* W2b = W2c + (size_t)bat * 65536;
  const unsigned short* V2b = V2c + (size_t)bat * 65536;

  // ===== fenced VMEM region: only our global_load_lds in flight =====
  asm volatile("s_waitcnt vmcnt(0)" ::: "memory");
  __builtin_amdgcn_sched_barrier(0);

  // prologue: chunks 0,1 of W
  stage_b(W2b + 0 * 8192 + w * 2048, &sB[0][w * 2048], lane);
  stage_b(W2b + 1 * 8192 + w * 2048, &sB[1][w * 2048], lane);

  f32x4 acc[4][4];
#pragma unroll
  for (int rt = 0; rt < 4; rt++)
#pragma unroll
    for (int nt = 0; nt < 4; nt++) acc[rt][nt] = (f32x4){0.f, 0.f, 0.f, 0.f};

  // ---- GEMM-A: scores = S @ W2 (8 chunks, dbuf; stage before MFMAs)
#pragma unroll
  for (int q = 0; q < 8; q++) {
    asm volatile("s_waitcnt vmcnt(4)" ::: "memory");  // chunk q arrived
    __builtin_amdgcn_sched_barrier(0);
    const unsigned short* bb = &sB[q & 1][w * 2048];
    short8v a[4], bf[4];
#pragma unroll
    for (int rt = 0; rt < 4; rt++)
      a[rt] = *(const short8v*)(sA + (rt * 16 + l16) * LDA + q * 32 + lhi * 8);
#pragma unroll
    for (int nt = 0; nt < 4; nt++)
      bf[nt] = *(const short8v*)(bb + nt * 512 + lane * 8);
    asm volatile("s_waitcnt lgkmcnt(0)" ::: "memory");  // frags in regs
    __builtin_amdgcn_sched_barrier(0);
    if (q < 6)
      stage_b(W2b + (q + 2) * 8192 + w * 2048, &sB[q & 1][w * 2048], lane);
    else  // V chunks 0,1 issued under the exp phase
      stage_b(V2b + (q - 6) * 8192 + w * 2048, &sB[q & 1][w * 2048], lane);
    __builtin_amdgcn_sched_barrier(0);
#pragma unroll
    for (int rt = 0; rt < 4; rt++)
#pragma unroll
      for (int nt = 0; nt < 4; nt++)
        acc[rt][nt] = __builtin_amdgcn_mfma_f32_16x16x32_bf16(
            a[rt], bf[nt], acc[rt][nt], 0, 0, 0);
  }

  // ---- exp phase between raw barriers (NO vmcnt drain: V0/V1 in flight)
  asm volatile("s_waitcnt lgkmcnt(0)" ::: "memory");
  __builtin_amdgcn_s_barrier();  // all waves done reading sA (S)
#pragma unroll
  for (int rt = 0; rt < 4; rt++)
#pragma unroll
    for (int nt = 0; nt < 4; nt++)
#pragma unroll
      for (int rg = 0; rg < 4; rg++)
        sA[(rt * 16 + lhi * 4 + rg) * LDA + (w * 64 + nt * 16 + l16)] =
            f2bf(__expf(acc[rt][nt][rg] + bnv[nt]));
  asm volatile("s_waitcnt lgkmcnt(0)" ::: "memory");
  __builtin_amdgcn_s_barrier();  // P visible to all waves

  // ---- GEMM-B: o = P_un @ V2, plus P row-sums via ones-MFMA
  short8v onesv;
#pragma unroll
  for (int j = 0; j < 8; j++) onesv[j] = (short)0x3F80;  // bf16 1.0
  f32x4 ps[4];
#pragma unroll
  for (int rt = 0; rt < 4; rt++) {
    ps[rt] = (f32x4){0.f, 0.f, 0.f, 0.f};
#pragma unroll
    for (int nt = 0; nt < 4; nt++) acc[rt][nt] = (f32x4){0.f, 0.f, 0.f, 0.f};
  }
#pragma unroll
  for (int q = 0; q < 8; q++) {
    if (q < 7) {
      asm volatile("s_waitcnt vmcnt(4)" ::: "memory");
    } else {
      asm volatile("s_waitcnt vmcnt(0)" ::: "memory");
    }
    __builtin_amdgcn_sched_barrier(0);
    const unsigned short* bb = &sB[q & 1][w * 2048];
    short8v a[4], bf[4];
#pragma unroll
    for (int rt = 0; rt < 4; rt++)
      a[rt] = *(const short8v*)(sA + (rt * 16 + l16) * LDA + q * 32 + lhi * 8);
#pragma unroll
    for (int nt = 0; nt < 4; nt++)
      bf[nt] = *(const short8v*)(bb + nt * 512 + lane * 8);
    asm volatile("s_waitcnt lgkmcnt(0)" ::: "memory");
    __builtin_amdgcn_sched_barrier(0);
    if (q < 6)
      stage_b(V2b + (q + 2) * 8192 + w * 2048, &sB[q & 1][w * 2048], lane);
    __builtin_amdgcn_sched_barrier(0);
#pragma unroll
    for (int rt = 0; rt < 4; rt++) {
#pragma unroll
      for (int nt = 0; nt < 4; nt++)
        acc[rt][nt] = __builtin_amdgcn_mfma_f32_16x16x32_bf16(
            a[rt], bf[nt], acc[rt][nt], 0, 0, 0);
      ps[rt] = __builtin_amdgcn_mfma_f32_16x16x32_bf16(a[rt], onesv, ps[rt],
                                                       0, 0, 0);
    }
  }
  __builtin_amdgcn_sched_barrier(0);
  // ===== end fenced region =====

  // ---- epilogue: o/rowsum + bo + S residual (f32), LN partial sums
  float bov[4], gv[4], bev[4];
#pragma unroll
  for (int nt = 0; nt < 4; nt++) {
    const int col = w * 64 + nt * 16 + l16;
    bov[nt] = bo[col];
    gv[nt] = gamma[col];
    bev[nt] = beta[col];
  }
#pragma unroll
  for (int rt = 0; rt < 4; rt++)
#pragma unroll
    for (int rg = 0; rg < 4; rg++) {
      const int row = rt * 16 + lhi * 4 + rg;
      const float invr = 1.f / ps[rt][rg];
      const float* Srow = Sblk + row * 256;
      float s1 = 0.f, s2 = 0.f;
#pragma unroll
      for (int nt = 0; nt < 4; nt++) {
        const int col = w * 64 + nt * 16 + l16;
        const float val = acc[rt][nt][rg] * invr + bov[nt] + Srow[col];
        acc[rt][nt][rg] = val;
        s1 += val;
        s2 = fmaf(val, val, s2);
      }
      s1 += __shfl_xor(s1, 1); s2 += __shfl_xor(s2, 1);
      s1 += __shfl_xor(s1, 2); s2 += __shfl_xor(s2, 2);
      s1 += __shfl_xor(s1, 4); s2 += __shfl_xor(s2, 4);
      s1 += __shfl_xor(s1, 8); s2 += __shfl_xor(s2, 8);
      if (l16 == 0) { sRed[row * 8 + w] = s1; sRed[row * 8 + 4 + w] = s2; }
    }
  __syncthreads();  // B4

  float* O = out + base;
#pragma unroll
  for (int rt = 0; rt < 4; rt++)
#pragma unroll
    for (int rg = 0; rg < 4; rg++) {
      const int row = rt * 16 + lhi * 4 + rg;
      f32x4 sa = *(f32x4*)(sRed + row * 8);
      f32x4 sq = *(f32x4*)(sRed + row * 8 + 4);
      const float mean = (sa[0] + sa[1] + sa[2] + sa[3]) * (1.f / 256.f);
      const float ex2 = (sq[0] + sq[1] + sq[2] + sq[3]) * (1.f / 256.f);
      const float rstd = rsqrtf(ex2 - mean * mean + 1e-5f);
      float* Orow = O + row * 256;
#pragma unroll
      for (int nt = 0; nt < 4; nt++) {
        const int col = w * 64 + nt * 16 + l16;
        Orow[col] = (acc[rt][nt][rg] - mean) * rstd * gv[nt] + bev[nt];
      }
    }
}

extern "C" void kernel_launch(void* const* d_in, const int* in_sizes, int n_in,
                              void* d_out, int out_size, void* d_ws, size_t ws_size,
                              hipStream_t stream) {
  const float* hs    = (const float*)d_in[0];
  const float* S     = (const float*)d_in[1];
  const float* Wq    = (const float*)d_in[2];
  const float* bq    = (const float*)d_in[3];
  const float* Wk    = (const float*)d_in[4];
  const float* bk    = (const float*)d_in[5];
  const float* Wv    = (const float*)d_in[6];
  const float* bv    = (const float*)d_in[7];
  const float* Wo    = (const float*)d_in[8];
  const float* bo    = (const float*)d_in[9];
  const float* gamma = (const float*)d_in[10];
  const float* beta  = (const float*)d_in[11];

  unsigned short* W2c = (unsigned short*)d_ws;          // 8*256*256 bf16 = 1MB
  unsigned short* V2c = W2c + 8 * 256 * 256;            // 1MB
  float* WA  = (float*)(V2c + 8 * 256 * 256);           // 256KB
  float* WB  = WA + 256 * 256;                          // 256KB
  float* wb2 = WB + 256 * 256;                          // 1KB
  float* cq  = wb2 + 256;
  float* cv  = cq + 256;
  float* cb  = cv + 256;
  float* bnp = cb + 256;                                // 8*256 f32

  make_w<<<256, 256, 0, stream>>>(Wq, Wk, Wv, Wo, bq, bk, bv, WA, WB, wb2, cq,
                                  cv, cb);
  prep2<<<256, 256, 0, stream>>>(hs, WA, WB, wb2, cq, cv, cb, W2c, V2c, bnp);
  pair_attn10<<<8192, 256, 0, stream>>>(S, bo, gamma, beta, bnp, W2c, V2c,
                                        (float*)d_out);
}